// Round 1
// 455.856 us; speedup vs baseline: 1.2741x; 1.2741x over previous
//
#include <hip/hip_runtime.h>
#include <hip/hip_fp16.h>

constexpr int C = 128;
constexpr int N = 4096;
constexpr int B = 4;

typedef _Float16 f16x8 __attribute__((ext_vector_type(8)));
typedef _Float16 f16x4 __attribute__((ext_vector_type(4)));
typedef float    f32x4 __attribute__((ext_vector_type(4)));

// ---------------------------------------------------------------------------
// One-shot weight convert fp32 -> f16 into workspace, concatenated:
// [w1(16K) | w2(16K) | wv(64K) | wt(64K) | wqk(16K)] elements.
// grid 176, 256 thr; each thread converts one float4.
// ---------------------------------------------------------------------------
__global__ __launch_bounds__(256) void k_wcvt(const float* __restrict__ w1,
                                              const float* __restrict__ w2,
                                              const float* __restrict__ wv,
                                              const float* __restrict__ wt,
                                              const float* __restrict__ wqk,
                                              _Float16* __restrict__ WF) {
  const int g = blockIdx.x * 256 + threadIdx.x;   // float4 index
  const float* src; int off;
  if (g < 4096)       { src = w1;  off = g; }
  else if (g < 8192)  { src = w2;  off = g - 4096; }
  else if (g < 24576) { src = wv;  off = g - 8192; }
  else if (g < 40960) { src = wt;  off = g - 24576; }
  else                { src = wqk; off = g - 40960; }
  const float4 v = ((const float4*)src)[off];
  f16x4 h = {(_Float16)v.x, (_Float16)v.y, (_Float16)v.z, (_Float16)v.w};
  *(f16x4*)&WF[(size_t)g * 4] = h;
}

// ---------------------------------------------------------------------------
// Mask compaction: exclusive prefix sum of (mask!=0) per batch + valid count.
// grid B, 1024 thr (4 elements/thread).
// ---------------------------------------------------------------------------
__global__ __launch_bounds__(1024) void k_mask(const int* __restrict__ mask,
                                               int* __restrict__ psum,
                                               int* __restrict__ nvb) {
  const int b = blockIdx.x, tid = threadIdx.x;
  __shared__ int wsum[16];
  const int4 mv = *(const int4*)&mask[b * N + tid * 4];
  const int m0 = (mv.x != 0), m1 = (mv.y != 0), m2 = (mv.z != 0), m3 = (mv.w != 0);
  const int s0 = m0, s1 = s0 + m1, s2 = s1 + m2, s3 = s2 + m3;
  const int lane = tid & 63, w = tid >> 6;
  int sc = s3;
#pragma unroll
  for (int o = 1; o < 64; o <<= 1) {
    const int v = __shfl_up(sc, o, 64);
    if (lane >= o) sc += v;
  }
  if (lane == 63) wsum[w] = sc;
  __syncthreads();
  if (tid < 16) {
    int v = wsum[tid];
#pragma unroll
    for (int o = 1; o < 16; o <<= 1) {
      const int u = __shfl_up(v, o, 64);
      if (tid >= o) v += u;
    }
    wsum[tid] = v;
  }
  __syncthreads();
  const int excl = ((w > 0) ? wsum[w - 1] : 0) + sc - s3;
  int4 pv;
  pv.x = excl; pv.y = excl + s0; pv.z = excl + s1; pv.w = excl + s2;
  *(int4*)&psum[b * N + tid * 4] = pv;
  if (tid == 0) nvb[b] = wsum[15];
}

// ---------------------------------------------------------------------------
// MFMA projection GEMM. Y[b,o,n] = sum_c W[o,c]*X[b,c,n] (+bias), fp32 out.
// grid (N/64, 2, B), block 512.
// ---------------------------------------------------------------------------
template<bool BIAS, bool STAT>
__global__ __launch_bounds__(512) void k_gwm(const _Float16* __restrict__ WF,
                                             const float* __restrict__ X,
                                             const float* __restrict__ bias,
                                             float* __restrict__ Y,
                                             float* __restrict__ bnpart) {
  __shared__ _Float16 XT[64 * 136];          // [n][c], stride 136 (16B-aligned rows)
  __shared__ float statP[4][64], statQ[4][64];
  const int tid = threadIdx.x;
  const int n0 = blockIdx.x * 64, oh = blockIdx.y, b = blockIdx.z;
  const float* Xb = X + (size_t)(b * C) * N + n0;
#pragma unroll
  for (int i = 0; i < 4; i++) {              // 2048 float4: c=idx>>4, q=idx&15
    const int idx = tid + i * 512;
    const int c = idx >> 4, q = idx & 15;
    const float4 v = *(const float4*)&Xb[(size_t)c * N + q * 4];
    XT[(q * 4 + 0) * 136 + c] = (_Float16)v.x;
    XT[(q * 4 + 1) * 136 + c] = (_Float16)v.y;
    XT[(q * 4 + 2) * 136 + c] = (_Float16)v.z;
    XT[(q * 4 + 3) * 136 + c] = (_Float16)v.w;
  }
  __syncthreads();
  const int w = tid >> 6, lane = tid & 63, quad = lane >> 4, lr = lane & 15;
  const int nt = w & 3, og = w >> 2;
  const int ob[2] = {oh * 64 + og * 16, oh * 64 + (og + 2) * 16};
  f16x8 aW[2][4];
#pragma unroll
  for (int t = 0; t < 2; t++)
#pragma unroll
    for (int kc = 0; kc < 4; kc++)
      aW[t][kc] = *(const f16x8*)&WF[(size_t)(ob[t] + lr) * 128 + kc * 32 + quad * 8];
  f32x4 acc[2];
  acc[0] = (f32x4){0.f, 0.f, 0.f, 0.f};
  acc[1] = (f32x4){0.f, 0.f, 0.f, 0.f};
#pragma unroll
  for (int kc = 0; kc < 4; kc++) {
    const f16x8 bf = *(const f16x8*)&XT[(nt * 16 + lr) * 136 + kc * 32 + quad * 8];
    acc[0] = __builtin_amdgcn_mfma_f32_16x16x32_f16(aW[0][kc], bf, acc[0], 0, 0, 0);
    acc[1] = __builtin_amdgcn_mfma_f32_16x16x32_f16(aW[1][kc], bf, acc[1], 0, 0, 0);
  }
#pragma unroll
  for (int t = 0; t < 2; t++) {
#pragma unroll
    for (int r = 0; r < 4; r++) {
      const int o = ob[t] + quad * 4 + r;
      const float val = acc[t][r] + (BIAS ? bias[o] : 0.f);
      Y[(size_t)(b * C + o) * N + n0 + nt * 16 + lr] = val;
      if (STAT) {
        float s = val, q = val * val;
        s += __shfl_xor(s, 1, 64); q += __shfl_xor(q, 1, 64);
        s += __shfl_xor(s, 2, 64); q += __shfl_xor(q, 2, 64);
        s += __shfl_xor(s, 4, 64); q += __shfl_xor(q, 4, 64);
        s += __shfl_xor(s, 8, 64); q += __shfl_xor(q, 8, 64);
        if (lr == 0) { statP[nt][o - oh * 64] = s; statQ[nt][o - oh * 64] = q; }
      }
    }
  }
  if (STAT) {
    __syncthreads();
    if (tid < 64) {
      const int o = oh * 64 + tid;
      const float s = statP[0][tid] + statP[1][tid] + statP[2][tid] + statP[3][tid];
      const float q = statQ[0][tid] + statQ[1][tid] + statQ[2][tid] + statQ[3][tid];
      const int part = blockIdx.x * 4 + b;
      bnpart[o * 512 + part] = s;
      bnpart[o * 512 + 256 + part] = q;
    }
  }
}

// ---------------------------------------------------------------------------
// Fused XV + QT projection via MFMA.  Outputs:
//  - QT  [b][n][32]      (original n space; k_pv A-operand for all m columns)
//  - QTc [b][j][32]      (compacted: only valid n, j = psum[n])
//  - XVc [b][c][j]       (compacted XV, f16; pad columns stay zero)
//  - xvp [(b*C+o)][128]  per-block partial sums of XV over INVALID n (f32)
// grid (N/32, B), block 256.
// ---------------------------------------------------------------------------
__global__ __launch_bounds__(256) void k_qv(const _Float16* __restrict__ WFv,
                                            const _Float16* __restrict__ WFqk,
                                            const float* __restrict__ X,
                                            const float* __restrict__ bv,
                                            const int* __restrict__ mask,
                                            const int* __restrict__ psum,
                                            _Float16* __restrict__ XVc,
                                            _Float16* __restrict__ QT,
                                            _Float16* __restrict__ QTc,
                                            float* __restrict__ xvp) {
  __shared__ _Float16 XT[32 * 136];
  __shared__ float SP[2][128];
  const int tid = threadIdx.x;
  const int n0 = blockIdx.x * 32, b = blockIdx.y;
  const float* Xb = X + (size_t)(b * C) * N + n0;
#pragma unroll
  for (int i = 0; i < 4; i++) {              // 1024 float4: c=idx>>3, q=idx&7
    const int idx = tid + i * 256;
    const int c = idx >> 3, q = idx & 7;
    const float4 v = *(const float4*)&Xb[(size_t)c * N + q * 4];
    XT[(q * 4 + 0) * 136 + c] = (_Float16)v.x;
    XT[(q * 4 + 1) * 136 + c] = (_Float16)v.y;
    XT[(q * 4 + 2) * 136 + c] = (_Float16)v.z;
    XT[(q * 4 + 3) * 136 + c] = (_Float16)v.w;
  }
  __syncthreads();
  const int w = tid >> 6, lane = tid & 63, quad = lane >> 4, lr = lane & 15;
  const int nt = w & 1, og = w >> 1;
  const int n = n0 + nt * 16 + lr;
  const int vld = mask[b * N + n] != 0;
  const int jc = psum[b * N + n];
  f32x4 acc[5];
  const _Float16* Aptr[5];
  int otl[5];
#pragma unroll
  for (int j = 0; j < 5; j++) {
    acc[j] = (f32x4){0.f, 0.f, 0.f, 0.f};
    const int ot = og + 2 * j;
    otl[j] = ot;
    Aptr[j] = (ot < 8) ? (WFv + (size_t)(ot * 16 + lr) * 128)
                       : (WFqk + (size_t)((ot - 8) * 16 + lr) * 128);
  }
#pragma unroll
  for (int kc = 0; kc < 4; kc++) {
    const f16x8 bf = *(const f16x8*)&XT[(nt * 16 + lr) * 136 + kc * 32 + quad * 8];
#pragma unroll
    for (int j = 0; j < 5; j++) {
      const f16x8 a = *(const f16x8*)&Aptr[j][kc * 32 + quad * 8];
      acc[j] = __builtin_amdgcn_mfma_f32_16x16x32_f16(a, bf, acc[j], 0, 0, 0);
    }
  }
#pragma unroll
  for (int j = 0; j < 5; j++) {
    const int ot = otl[j];
    if (ot < 8) {
      float v[4];
#pragma unroll
      for (int r = 0; r < 4; r++) v[r] = acc[j][r] + bv[ot * 16 + quad * 4 + r];
      if (vld) {
#pragma unroll
        for (int r = 0; r < 4; r++)
          XVc[(size_t)(b * C + ot * 16 + quad * 4 + r) * N + jc] = (_Float16)v[r];
      }
      float s[4];
#pragma unroll
      for (int r = 0; r < 4; r++) s[r] = vld ? 0.f : v[r];
#pragma unroll
      for (int o = 1; o <= 8; o <<= 1) {
#pragma unroll
        for (int r = 0; r < 4; r++) s[r] += __shfl_xor(s[r], o, 64);
      }
      if (lr == 0) {
#pragma unroll
        for (int r = 0; r < 4; r++) SP[nt][ot * 16 + quad * 4 + r] = s[r];
      }
    } else {
      f16x4 qv;
#pragma unroll
      for (int r = 0; r < 4; r++) qv[r] = (_Float16)acc[j][r];
      const int qo = (ot - 8) * 16 + quad * 4;
      *(f16x4*)&QT[((size_t)b * N + n) * 32 + qo] = qv;
      if (vld) *(f16x4*)&QTc[((size_t)b * N + jc) * 32 + qo] = qv;
    }
  }
  __syncthreads();
  if (tid < 128)
    xvp[(size_t)(b * C + tid) * 128 + blockIdx.x] = SP[0][tid] + SP[1][tid];
}

// ---------------------------------------------------------------------------
// Reduce xvp partials -> xvi[b*C+c] = sum over invalid n of xv[c,n].
// grid (C, B), 64 thr.
// ---------------------------------------------------------------------------
__global__ __launch_bounds__(64) void k_xvr(const float* __restrict__ xvp,
                                            float* __restrict__ xvi) {
  const int c = blockIdx.x, b = blockIdx.y, tid = threadIdx.x;
  const float* src = xvp + (size_t)(b * C + c) * 128;
  float v = src[tid] + src[tid + 64];
#pragma unroll
  for (int o = 1; o <= 32; o <<= 1) v += __shfl_xor(v, o, 64);
  if (tid == 0) xvi[b * C + c] = v;
}

// ---------------------------------------------------------------------------
// Row stats over COMPACTED space (valid n x valid m): Gram area ~ (Nv/N)^2.
// Pad rows (j in [Nv, Nvp64)) are zero in QTc; they get rowsi=0.
// grid (N/64, B), block 512; blocks past Nvp64 exit.
// ---------------------------------------------------------------------------
__global__ __launch_bounds__(512) void k_sm(const _Float16* __restrict__ QTc,
                                            const int* __restrict__ nvb,
                                            float* __restrict__ rowmax,
                                            float* __restrict__ rowsi) {
  const int b = blockIdx.y;
  const int Nv = nvb[b];
  const int NvpB = (Nv + 63) & ~63;
  const int n0 = blockIdx.x * 64;
  if (n0 >= NvpB) return;
  __shared__ float mb[N];          // 0 (valid compacted m) or -1e30 (pad)
  __shared__ float red[2][64];
  __shared__ float rmS[64];
  const int tid = threadIdx.x;
  const _Float16* Qb = QTc + (size_t)b * N * 32;
#pragma unroll
  for (int i = 0; i < 8; i++) {
    const int v = tid + i * 512;
    mb[v] = (v < Nv) ? 0.0f : -1e30f;
  }
  const int w = tid >> 6, lane = tid & 63, quad = lane >> 4, lr = lane & 15;
  const int nw = (w & 3) * 16, mh = (w >> 2) * 64;
  const f16x8 aF = *(const f16x8*)&Qb[(size_t)(n0 + nw + lr) * 32 + quad * 8];
  __syncthreads();
  float mx[4] = {-3e38f, -3e38f, -3e38f, -3e38f};
  for (int ms = 0; ms < NvpB; ms += 128) {
#pragma unroll
    for (int t = 0; t < 4; t++) {
      const int mrow = ms + mh + t * 16 + lr;
      const f16x8 bF = *(const f16x8*)&Qb[(size_t)mrow * 32 + quad * 8];
      f32x4 d = (f32x4){0.f, 0.f, 0.f, 0.f};
      d = __builtin_amdgcn_mfma_f32_16x16x32_f16(aF, bF, d, 0, 0, 0);
      const float bias = mb[mrow];
#pragma unroll
      for (int r = 0; r < 4; r++) mx[r] = fmaxf(mx[r], d[r] + bias);
    }
  }
#pragma unroll
  for (int r = 0; r < 4; r++) {
    float v = mx[r];
    v = fmaxf(v, __shfl_xor(v, 1, 64));
    v = fmaxf(v, __shfl_xor(v, 2, 64));
    v = fmaxf(v, __shfl_xor(v, 4, 64));
    v = fmaxf(v, __shfl_xor(v, 8, 64));
    mx[r] = v;
  }
  if (lr == 0)
#pragma unroll
    for (int r = 0; r < 4; r++) red[w >> 2][nw + quad * 4 + r] = mx[r];
  __syncthreads();
  if (tid < 64) rmS[tid] = fmaxf(red[0][tid], red[1][tid]);
  __syncthreads();
  float rmr[4];
#pragma unroll
  for (int r = 0; r < 4; r++) rmr[r] = rmS[nw + quad * 4 + r];
  float s[4] = {0.f, 0.f, 0.f, 0.f};
  for (int ms = 0; ms < NvpB; ms += 128) {
#pragma unroll
    for (int t = 0; t < 4; t++) {
      const int mrow = ms + mh + t * 16 + lr;
      const f16x8 bF = *(const f16x8*)&Qb[(size_t)mrow * 32 + quad * 8];
      f32x4 d = (f32x4){0.f, 0.f, 0.f, 0.f};
      d = __builtin_amdgcn_mfma_f32_16x16x32_f16(aF, bF, d, 0, 0, 0);
      const float bias = mb[mrow];
#pragma unroll
      for (int r = 0; r < 4; r++) s[r] += __expf(d[r] + bias - rmr[r]);
    }
  }
#pragma unroll
  for (int r = 0; r < 4; r++) {
    float v = s[r];
    v += __shfl_xor(v, 1, 64);
    v += __shfl_xor(v, 2, 64);
    v += __shfl_xor(v, 4, 64);
    v += __shfl_xor(v, 8, 64);
    s[r] = v;
  }
  __syncthreads();
  if (lr == 0)
#pragma unroll
    for (int r = 0; r < 4; r++) red[w >> 2][nw + quad * 4 + r] = s[r];
  __syncthreads();
  if (tid < 64) {
    const int row = n0 + tid;
    const float tot = red[0][tid] + red[1][tid];
    const bool valid = row < Nv;
    rowmax[b * N + row] = valid ? rmS[tid] : 1e30f;
    rowsi[b * N + row] = valid ? (1.0f / tot) : 0.0f;
  }
}

// ---------------------------------------------------------------------------
// Fused Gram->exp->PV with COMPACTED n loop (valid rows only, ~half steps).
// m columns stay in ORIGINAL space (vmb bias handles invalid m -> P=0).
// Invalid-row uniform attn contribution added analytically in the epilogue:
//   x_r = (acc + xvInvSum/4096) / (1e-9 + colS + ninv/4096)
// grid (N/32, B), block 512.
// ---------------------------------------------------------------------------
__global__ __launch_bounds__(512, 4) void k_pv(const _Float16* __restrict__ QT,
                                               const _Float16* __restrict__ QTc,
                                               const _Float16* __restrict__ XVc,
                                               const float* __restrict__ H,
                                               const int* __restrict__ mask,
                                               const float* __restrict__ rowmax,
                                               const float* __restrict__ rowsi,
                                               const int* __restrict__ nvb,
                                               const float* __restrict__ xvi,
                                               float* __restrict__ Td) {
  __shared__ _Float16 XVs[2][128 * 72];
  __shared__ _Float16 Ps[2][32 * 72];
  __shared__ float colPart[4][32];
  __shared__ float colS[32];
  const int tid = threadIdx.x;
  const int m0 = blockIdx.x * 32, b = blockIdx.y;
  const int Nv = nvb[b];
  const int ns = ((Nv + 63) & ~63) >> 6;
  const _Float16* Qa = QT + (size_t)b * N * 32;
  const _Float16* Qc = QTc + (size_t)b * N * 32;
  const _Float16* XVb = XVc + (size_t)(b * C) * N;
  const float* rmB = rowmax + b * N;
  const float* riB = rowsi + b * N;
  const int w = tid >> 6, lane = tid & 63, quad = lane >> 4, lr = lane & 15;
  const int msub = w & 1, nsub = w >> 1;
  const f16x8 aG = *(const f16x8*)&Qa[(size_t)(m0 + msub * 16 + lr) * 32 + quad * 8];
  float vmb[4];
#pragma unroll
  for (int r = 0; r < 4; r++)
    vmb[r] = (mask[b * N + m0 + msub * 16 + quad * 4 + r] != 0) ? 0.0f : -1e30f;
  const int sc0 = tid >> 3, sh0 = tid & 7;   // XV staging rows (2 vec/thread)
  const int sc1 = sc0 + 64;
  f32x4 acc[2];
  acc[0] = (f32x4){0.f, 0.f, 0.f, 0.f};
  acc[1] = (f32x4){0.f, 0.f, 0.f, 0.f};
  float cs[4] = {0.f, 0.f, 0.f, 0.f};

  auto produce = [&](int k0, int bf) {
    const int nn = k0 + nsub * 16 + lr;
    const f16x8 bG = *(const f16x8*)&Qc[(size_t)nn * 32 + quad * 8];
    const f16x8 xv0 = *(const f16x8*)&XVb[(size_t)sc0 * N + k0 + sh0 * 8];
    const f16x8 xv1 = *(const f16x8*)&XVb[(size_t)sc1 * N + k0 + sh0 * 8];
    const float rmv = rmB[nn], riv = riB[nn];
    f32x4 e = (f32x4){0.f, 0.f, 0.f, 0.f};
    e = __builtin_amdgcn_mfma_f32_16x16x32_f16(aG, bG, e, 0, 0, 0);
    *(f16x8*)&XVs[bf][sc0 * 72 + sh0 * 8] = xv0;
    *(f16x8*)&XVs[bf][sc1 * 72 + sh0 * 8] = xv1;
#pragma unroll
    for (int r = 0; r < 4; r++) {
      const float p = __expf(e[r] - rmv + vmb[r]) * riv;   // pad rows: riv=0 -> p=0
      cs[r] += p;
      Ps[bf][(msub * 16 + quad * 4 + r) * 72 + nsub * 16 + lr] = (_Float16)p;
    }
  };
  auto consume = [&](int bf) {
    const int c0 = w * 16;
    const f16x8 a0 = *(const f16x8*)&XVs[bf][(c0 + lr) * 72 + quad * 8];
    const f16x8 a1 = *(const f16x8*)&XVs[bf][(c0 + lr) * 72 + 32 + quad * 8];
    const f16x8 b00 = *(const f16x8*)&Ps[bf][lr * 72 + quad * 8];
    const f16x8 b01 = *(const f16x8*)&Ps[bf][lr * 72 + 32 + quad * 8];
    const f16x8 b10 = *(const f16x8*)&Ps[bf][(16 + lr) * 72 + quad * 8];
    const f16x8 b11 = *(const f16x8*)&Ps[bf][(16 + lr) * 72 + 32 + quad * 8];
    acc[0] = __builtin_amdgcn_mfma_f32_16x16x32_f16(a0, b00, acc[0], 0, 0, 0);
    acc[0] = __builtin_amdgcn_mfma_f32_16x16x32_f16(a1, b01, acc[0], 0, 0, 0);
    acc[1] = __builtin_amdgcn_mfma_f32_16x16x32_f16(a0, b10, acc[1], 0, 0, 0);
    acc[1] = __builtin_amdgcn_mfma_f32_16x16x32_f16(a1, b11, acc[1], 0, 0, 0);
  };

  if (ns > 0) produce(0, 0);
  __syncthreads();
  for (int it = 0; it < ns; it += 2) {
    if (it + 1 < ns) produce((it + 1) * 64, 1);
    consume(0);
    __syncthreads();
    if (it + 1 < ns) {
      if (it + 2 < ns) produce((it + 2) * 64, 0);
      consume(1);
      __syncthreads();
    }
  }
#pragma unroll
  for (int r = 0; r < 4; r++) {
    float v = cs[r];
    v += __shfl_xor(v, 1, 64);
    v += __shfl_xor(v, 2, 64);
    v += __shfl_xor(v, 4, 64);
    v += __shfl_xor(v, 8, 64);
    cs[r] = v;
  }
  if (lr == 0)
#pragma unroll
    for (int r = 0; r < 4; r++) colPart[nsub][msub * 16 + quad * 4 + r] = cs[r];
  __syncthreads();
  if (tid < 32)
    colS[tid] = colPart[0][tid] + colPart[1][tid] + colPart[2][tid] + colPart[3][tid];
  __syncthreads();
  const float ninvq = (float)(N - Nv) * 0.000244140625f;   // ninv/4096
  const float rdiv0 = 1.0f / (1e-9f + colS[lr] + ninvq);
  const float rdiv1 = 1.0f / (1e-9f + colS[16 + lr] + ninvq);
  const int cg = b * C + w * 16 + quad * 4;
#pragma unroll
  for (int r = 0; r < 4; r++) {
    const float xadd = xvi[cg + r] * 0.000244140625f;      // xvInvSum/4096
    const size_t gi0 = (size_t)(cg + r) * N + m0 + lr;
    Td[gi0] = H[gi0] - (acc[0][r] + xadd) * rdiv0;
    const size_t gi1 = (size_t)(cg + r) * N + m0 + 16 + lr;
    Td[gi1] = H[gi1] - (acc[1][r] + xadd) * rdiv1;
  }
}

// ---------------------------------------------------------------------------
// Apply BN+ReLU (+residual, +write output slice). grid 2048, 256 thr, float4.
// ---------------------------------------------------------------------------
template<bool RES>
__global__ __launch_bounds__(256) void k_apply(const float* __restrict__ T2,
                                               const float* __restrict__ bnpart,
                                               const float* __restrict__ gamma,
                                               const float* __restrict__ beta,
                                               float* __restrict__ H,
                                               float* __restrict__ Out) {
  __shared__ float rs[4], rq[4], bc[2];
  const int tid = threadIdx.x;
  const int f = (blockIdx.x * 256 + tid) * 4;
  const int c = (blockIdx.x >> 2) & 127;
  float s = bnpart[c * 512 + tid];
  float q = bnpart[c * 512 + 256 + tid];
#pragma unroll
  for (int o = 1; o <= 32; o <<= 1) { s += __shfl_xor(s, o, 64); q += __shfl_xor(q, o, 64); }
  if ((tid & 63) == 0) { rs[tid >> 6] = s; rq[tid >> 6] = q; }
  __syncthreads();
  if (tid == 0) {
    const float st = rs[0] + rs[1] + rs[2] + rs[3];
    const float qt = rq[0] + rq[1] + rq[2] + rq[3];
    const float inv = 1.0f / (B * N);
    const float mean = st * inv;
    const float var = qt * inv - mean * mean;   // biased, like torch BN
    const float sc = gamma[c] * rsqrtf(var + 1e-5f);
    bc[0] = sc;
    bc[1] = beta[c] - mean * sc;
  }
  __syncthreads();
  const float sc = bc[0], sh = bc[1];
  const float4 t = *(const float4*)&T2[f];
  float4 r;
  r.x = fmaxf(t.x * sc + sh, 0.f);
  r.y = fmaxf(t.y * sc + sh, 0.f);
  r.z = fmaxf(t.z * sc + sh, 0.f);
  r.w = fmaxf(t.w * sc + sh, 0.f);
  if (RES) {
    const float4 h = *(const float4*)&H[f];
    r.x += h.x; r.y += h.y; r.z += h.z; r.w += h.w;
    *(float4*)&H[f] = r;
    const int b = f >> 19;                // f / (C*N)
    const int rem = f & (C * N - 1);      // c*N + n
    *(float4*)&Out[(size_t)b * (4 * C * N) + rem] = r;
  } else {
    *(float4*)&H[f] = r;
  }
}

// ---------------------------------------------------------------------------
extern "C" void kernel_launch(void* const* d_in, const int* in_sizes, int n_in,
                              void* d_out, int out_size, void* d_ws, size_t ws_size,
                              hipStream_t stream) {
  const float* x    = (const float*)d_in[0];
  const int*   mask = (const int*)  d_in[1];
  const float* w1   = (const float*)d_in[2];
  const float* g1   = (const float*)d_in[3];
  const float* b1   = (const float*)d_in[4];
  const float* w2   = (const float*)d_in[5];
  const float* g2   = (const float*)d_in[6];
  const float* b2   = (const float*)d_in[7];
  const float* wqk  = (const float*)d_in[8];
  const float* wv   = (const float*)d_in[9];
  const float* bv   = (const float*)d_in[10];
  const float* wt   = (const float*)d_in[11];
  const float* bt   = (const float*)d_in[12];
  const float* sg   = (const float*)d_in[13];
  const float* sb   = (const float*)d_in[14];
  float* out = (float*)d_out;

  char* p = (char*)d_ws;
  auto alloc = [&](size_t bytes) { char* r = p; p += (bytes + 255) & ~(size_t)255; return r; };
  float*    H      = (float*)   alloc((size_t)B * C * N * 4);
  float*    T2     = (float*)   alloc((size_t)B * C * N * 4);
  float*    Td     = (float*)   alloc((size_t)B * C * N * 4);
  _Float16* QT     = (_Float16*)alloc((size_t)B * N * 32 * 2);
  _Float16* QTc    = (_Float16*)alloc((size_t)B * N * 32 * 2);
  _Float16* XVc    = (_Float16*)alloc((size_t)B * C * N * 2);
  float*    rowmax = (float*)   alloc((size_t)B * N * 4);
  float*    rowsi  = (float*)   alloc((size_t)B * N * 4);
  float*    bnpart = (float*)   alloc((size_t)C * 512 * 4);
  int*      psum   = (int*)     alloc((size_t)B * N * 4);
  int*      nvb    = (int*)     alloc(256);
  float*    xvp    = (float*)   alloc((size_t)B * C * 128 * 4);
  float*    xvi    = (float*)   alloc((size_t)B * C * 4);
  _Float16* WF     = (_Float16*)alloc((size_t)180224 * 2);
  (void)ws_size;
  _Float16* wf1  = WF;
  _Float16* wf2  = WF + 16384;
  _Float16* wfv  = WF + 32768;
  _Float16* wft  = WF + 98304;
  _Float16* wfqk = WF + 163840;

  // ---- one-shot setup: weight convert, mask compaction, pad zeroing ----
  k_wcvt<<<176, 256, 0, stream>>>(w1, w2, wv, wt, wqk, WF);
  k_mask<<<B, 1024, 0, stream>>>(mask, psum, nvb);
  hipMemsetAsync(QTc, 0, (size_t)B * N * 32 * 2, stream);
  hipMemsetAsync(XVc, 0, (size_t)B * C * N * 2, stream);

  // ---- stem: two conv1d(+BN+ReLU), MFMA, BN partials fused ----
  k_gwm<false, true><<<dim3(64, 2, B), 512, 0, stream>>>(wf1, x, nullptr, T2, bnpart);
  k_apply<false><<<2048, 256, 0, stream>>>(T2, bnpart, g1, b1, H, nullptr);
  k_gwm<false, true><<<dim3(64, 2, B), 512, 0, stream>>>(wf2, H, nullptr, T2, bnpart);
  k_apply<false><<<2048, 256, 0, stream>>>(T2, bnpart, g2, b2, H, nullptr);

  // ---- 4 chained offset-attention layers (compacted flash-style) ----
  for (int L = 0; L < 4; L++) {
    k_qv<<<dim3(128, B), 256, 0, stream>>>(wfv + (size_t)L * 16384, wfqk + (size_t)L * 4096,
                                           H, bv + L * C, mask, psum, XVc, QT, QTc, xvp);
    k_xvr<<<dim3(C, B), 64, 0, stream>>>(xvp, xvi);
    k_sm<<<dim3(64, B), 512, 0, stream>>>(QTc, nvb, rowmax, rowsi);
    k_pv<<<dim3(128, B), 512, 0, stream>>>(QT, QTc, XVc, H, mask, rowmax, rowsi, nvb, xvi, Td);
    k_gwm<true, true><<<dim3(64, 2, B), 512, 0, stream>>>(wft + (size_t)L * 16384, Td, bt + L * C, T2, bnpart);
    k_apply<true><<<2048, 256, 0, stream>>>(T2, bnpart, sg + L * C, sb + L * C, H, out + (size_t)L * C * N);
  }
}